// Round 8
// baseline (831.591 us; speedup 1.0000x reference)
//
#include <hip/hip_runtime.h>

#define N_NODES 100000
#define N_EDGES 3200000
#define N_GRAPHS 2048
#define MOL 78
#define HID 32
#define OUTD 128
#define BN_EPS 1e-5f

// Partition: buckets of 256 nodes (dst >> 8)
#define NBUCK ((N_NODES + 255) / 256)  // 391
#define BCAP2 9216                     // mean 8184, sigma ~90 -> +11 sigma
#define EPB 4096                       // edges per part1 block
#define P1_BLOCKS ((N_EDGES + EPB - 1) / EPB)  // 782

#define NPH 4                             // nodes per half-wave (matvec kernels)
#define CPL_BLOCKS (N_NODES / (8 * NPH))  // 3125 (exact)

// ---------------- CSR build: LDS-staged two-pass bucket sort ----------------

__global__ __launch_bounds__(256) void part1_kernel(const int* __restrict__ src,
                                                    const int* __restrict__ dst,
                                                    int* __restrict__ gcur,
                                                    int* __restrict__ staging) {
    __shared__ int hist[NBUCK];
    __shared__ int lofs[NBUCK];
    __shared__ int lcur[NBUCK];
    __shared__ int gb[NBUCK];
    __shared__ int pk[EPB];
    __shared__ unsigned short bkt[EPB];
    __shared__ int sc[256];
    const int t = threadIdx.x;
    const int base = blockIdx.x * EPB;
    const int nedge = min(EPB, N_EDGES - base);

    for (int i = t; i < NBUCK; i += 256) hist[i] = 0;
    __syncthreads();
    for (int i = t; i < nedge; i += 256) atomicAdd(&hist[dst[base + i] >> 8], 1);
    __syncthreads();

    int a0 = (2 * t < NBUCK) ? hist[2 * t] : 0;
    int a1 = (2 * t + 1 < NBUCK) ? hist[2 * t + 1] : 0;
    int tot = a0 + a1;
    sc[t] = tot;
    __syncthreads();
    for (int off = 1; off < 256; off <<= 1) {
        int add = (t >= off) ? sc[t - off] : 0;
        __syncthreads();
        sc[t] += add;
        __syncthreads();
    }
    int excl = sc[t] - tot;
    if (2 * t < NBUCK) { lofs[2 * t] = excl; lcur[2 * t] = excl; }
    if (2 * t + 1 < NBUCK) { lofs[2 * t + 1] = excl + a0; lcur[2 * t + 1] = excl + a0; }
    __syncthreads();

    for (int i = t; i < nedge; i += 256) {
        int d = dst[base + i];
        int s = src[base + i];
        int b = d >> 8;
        int p = atomicAdd(&lcur[b], 1);
        pk[p] = (s << 8) | (d & 255);
        bkt[p] = (unsigned short)b;
    }
    __syncthreads();

    for (int b = t; b < NBUCK; b += 256) {
        int c = lcur[b] - lofs[b];
        gb[b] = c ? atomicAdd(&gcur[b], c) : 0;
    }
    __syncthreads();

    for (int i = t; i < nedge; i += 256) {
        int b = bkt[i];
        staging[(size_t)b * BCAP2 + gb[b] + (i - lofs[b])] = pk[i];
    }
}

__global__ void csrbase_kernel(const int* __restrict__ gcur, int* __restrict__ bbase,
                               int* __restrict__ row_start) {
    int t = threadIdx.x;
    int a0 = (2 * t < NBUCK) ? gcur[2 * t] : 0;
    int a1 = (2 * t + 1 < NBUCK) ? gcur[2 * t + 1] : 0;
    int tot = a0 + a1;
    __shared__ int sc[256];
    sc[t] = tot;
    __syncthreads();
    for (int off = 1; off < 256; off <<= 1) {
        int add = (t >= off) ? sc[t - off] : 0;
        __syncthreads();
        sc[t] += add;
        __syncthreads();
    }
    int excl = sc[t] - tot;
    if (2 * t < NBUCK) bbase[2 * t] = excl;
    if (2 * t + 1 < NBUCK) bbase[2 * t + 1] = excl + a0;
    if (t == 0) row_start[N_NODES] = N_EDGES;
}

__global__ __launch_bounds__(256) void part2_kernel(const int* __restrict__ gcur,
                                                    const int* __restrict__ bbase,
                                                    const int* __restrict__ staging,
                                                    int* __restrict__ row_start,
                                                    int* __restrict__ csr) {
    int b = blockIdx.x, t = threadIdx.x;
    __shared__ int ldeg[256];
    __shared__ int lex[256];
    __shared__ int sc[256];
    ldeg[t] = 0;
    __syncthreads();
    int cnt = gcur[b];
    int base = bbase[b];
    const int* sp = staging + (size_t)b * BCAP2;
    for (int i = t; i < cnt; i += 256) atomicAdd(&ldeg[sp[i] & 255], 1);
    __syncthreads();
    int v = ldeg[t];
    sc[t] = v;
    __syncthreads();
    for (int off = 1; off < 256; off <<= 1) {
        int add = (t >= off) ? sc[t - off] : 0;
        __syncthreads();
        sc[t] += add;
        __syncthreads();
    }
    int excl = sc[t] - v;
    int node = b * 256 + t;
    if (node < N_NODES) row_start[node] = base + excl;
    lex[t] = base + excl;
    __syncthreads();
    for (int i = t; i < cnt; i += 256) {
        int pk = sp[i];
        int p = atomicAdd(&lex[pk & 255], 1);
        csr[p] = pk >> 8;
    }
}

// ---------------- Layer-0 projection (78 -> 32), thread-per-node ----------------

__global__ __launch_bounds__(256) void proj78_kernel(const float* __restrict__ in,
                                                     const float* __restrict__ W1,
                                                     float* __restrict__ y) {
    __shared__ float w1s[MOL * HID];
    for (int i = threadIdx.x; i < MOL * HID; i += 256) w1s[i] = W1[i];
    __syncthreads();
    const int node = blockIdx.x * 256 + threadIdx.x;
    if (node >= N_NODES) return;
    const float* row = in + (size_t)node * MOL;
    float acc[HID];
#pragma unroll
    for (int j = 0; j < HID; j++) acc[j] = 0.f;
    const float4* w1v = (const float4*)w1s;
    for (int k = 0; k < MOL; k++) {
        float xv = row[k];
#pragma unroll
        for (int q = 0; q < 8; q++) {
            float4 wv = w1v[k * 8 + q];
            acc[4 * q + 0] = fmaf(xv, wv.x, acc[4 * q + 0]);
            acc[4 * q + 1] = fmaf(xv, wv.y, acc[4 * q + 1]);
            acc[4 * q + 2] = fmaf(xv, wv.z, acc[4 * q + 2]);
            acc[4 * q + 3] = fmaf(xv, wv.w, acc[4 * q + 3]);
        }
    }
    float4* o = (float4*)(y + (size_t)node * HID);
#pragma unroll
    for (int q = 0; q < 8; q++)
        o[q] = make_float4(acc[4 * q], acc[4 * q + 1], acc[4 * q + 2], acc[4 * q + 3]);
}

// ---------------- Aggregation: pure 32-dim f32 sum over CSR (round-5 proven) --------
// One half-wave per node, 12500 blocks: 4 slots x 8 lanes x float4, unroll x2.

__global__ __launch_bounds__(256) void agg_kernel(const float* __restrict__ y,
                                                  const int* __restrict__ rs,
                                                  const int* __restrict__ csr,
                                                  float* __restrict__ agg) {
    int gt = blockIdx.x * blockDim.x + threadIdx.x;
    int node = gt >> 5;
    if (node >= N_NODES) return;
    int hl = threadIdx.x & 31;  // lane within half-wave
    int s = hl >> 3;            // edge slot 0..3
    int q = hl & 7;             // float4 quad (channels 4q..4q+3)
    const float4* rows = (const float4*)y;
    float4 acc = (s == 0) ? rows[(size_t)node * 8 + q] : make_float4(0.f, 0.f, 0.f, 0.f);
    int e0 = rs[node], e1 = rs[node + 1];
    int k = e0 + s;
    for (; k + 4 < e1; k += 8) {
        int j0 = csr[k];
        int j1 = csr[k + 4];
        float4 v0 = rows[(size_t)j0 * 8 + q];
        float4 v1 = rows[(size_t)j1 * 8 + q];
        acc.x += v0.x + v1.x;
        acc.y += v0.y + v1.y;
        acc.z += v0.z + v1.z;
        acc.w += v0.w + v1.w;
    }
    if (k < e1) {
        int j = csr[k];
        float4 v = rows[(size_t)j * 8 + q];
        acc.x += v.x;
        acc.y += v.y;
        acc.z += v.z;
        acc.w += v.w;
    }
#pragma unroll
    for (int m = 8; m <= 16; m <<= 1) {
        acc.x += __shfl_xor(acc.x, m, 32);
        acc.y += __shfl_xor(acc.y, m, 32);
        acc.z += __shfl_xor(acc.z, m, 32);
        acc.w += __shfl_xor(acc.w, m, 32);
    }
    if (s == 0) ((float4*)agg)[(size_t)node * 8 + q] = acc;
}

// ---------------- MLP second half, channel-per-lane ----------------
// Half-wave per NPH nodes; lane = channel. Coalesced row loads, W2 column in
// VGPRs, activation broadcast via LDS, BN stats lane-local -> LDS -> atomics.

__global__ __launch_bounds__(256) void mlp2cpl_kernel(const float* __restrict__ agg,
                                                      const float* __restrict__ B1,
                                                      const float* __restrict__ W2,
                                                      const float* __restrict__ B2,
                                                      float* __restrict__ out,
                                                      float* __restrict__ sums) {
    __shared__ float ldsv[8][NPH][HID];
    __shared__ float ssum[64];
    const int t = threadIdx.x;
    const int hw = t >> 5;
    const int c = t & 31;
    if (t < 64) ssum[t] = 0.f;
    float w2col[32];
#pragma unroll
    for (int k = 0; k < 32; k++) w2col[k] = W2[k * 32 + c];
    const float b1c = B1[c], b2c = B2[c];
    const int n0 = (blockIdx.x * 8 + hw) * NPH;
#pragma unroll
    for (int u = 0; u < NPH; u++) {
        float v = fmaxf(agg[(size_t)(n0 + u) * 32 + c] + b1c, 0.f);
        ldsv[hw][u][c] = v;
    }
    __syncthreads();
    float sl = 0.f, sq = 0.f;
#pragma unroll
    for (int u = 0; u < NPH; u++) {
        float h = b2c;
        const float4* vv4 = (const float4*)&ldsv[hw][u][0];
#pragma unroll
        for (int q = 0; q < 8; q++) {
            float4 vv = vv4[q];
            h = fmaf(vv.x, w2col[4 * q + 0], h);
            h = fmaf(vv.y, w2col[4 * q + 1], h);
            h = fmaf(vv.z, w2col[4 * q + 2], h);
            h = fmaf(vv.w, w2col[4 * q + 3], h);
        }
        h = fmaxf(h, 0.f);
        out[(size_t)(n0 + u) * 32 + c] = h;
        sl += h;
        sq += h * h;
    }
    atomicAdd(&ssum[c], sl);
    atomicAdd(&ssum[32 + c], sq);
    __syncthreads();
    if (t < 64) atomicAdd(&sums[t], ssum[t]);
}

// ---------------- Projection 32->32 with pre-folded affine (channel-per-lane) ------

__global__ __launch_bounds__(256) void proj32_kernel(const float* __restrict__ h,
                                                     const float* __restrict__ W1e,
                                                     const float* __restrict__ b1e,
                                                     float* __restrict__ y) {
    __shared__ float ldsh[8][NPH][32];
    const int t = threadIdx.x;
    const int hw = t >> 5;
    const int c = t & 31;
    float w1col[32];
#pragma unroll
    for (int k = 0; k < 32; k++) w1col[k] = W1e[k * 32 + c];
    const float bc = b1e[c];
    const int n0 = (blockIdx.x * 8 + hw) * NPH;
#pragma unroll
    for (int u = 0; u < NPH; u++) {
        int n = n0 + u;
        ldsh[hw][u][c] = h[(size_t)n * 32 + c];
    }
    __syncthreads();
#pragma unroll
    for (int u = 0; u < NPH; u++) {
        int n = n0 + u;
        float acc = bc;
        const float4* hh4 = (const float4*)&ldsh[hw][u][0];
#pragma unroll
        for (int q = 0; q < 8; q++) {
            float4 hh = hh4[q];
            acc = fmaf(hh.x, w1col[4 * q + 0], acc);
            acc = fmaf(hh.y, w1col[4 * q + 1], acc);
            acc = fmaf(hh.z, w1col[4 * q + 2], acc);
            acc = fmaf(hh.w, w1col[4 * q + 3], acc);
        }
        y[(size_t)n * 32 + c] = acc;
    }
}

// ---------------- BN finalize (+ optional fold into next layer's W1) ----------------

__global__ void bnfinW_kernel(const float* __restrict__ sums, const float* __restrict__ g,
                              const float* __restrict__ bt, float* __restrict__ scsh,
                              const float* __restrict__ W1src, float* __restrict__ w1eff,
                              float* __restrict__ b1eff) {
    __shared__ float s_sc[HID], s_sh[HID];
    int t = threadIdx.x;
    if (t < HID) {
        float m = sums[t] * (1.0f / N_NODES);
        float var = sums[HID + t] * (1.0f / N_NODES) - m * m;
        var = fmaxf(var, 0.f);
        float sc = g[t] * rsqrtf(var + BN_EPS);
        float sh = bt[t] - m * sc;
        scsh[t] = sc;
        scsh[HID + t] = sh;
        s_sc[t] = sc;
        s_sh[t] = sh;
    }
    __syncthreads();
    if (W1src) {
        for (int idx = t; idx < HID * HID; idx += 256)
            w1eff[idx] = s_sc[idx >> 5] * W1src[idx];
        if (t < HID) {
            float b = 0.f;
            for (int c = 0; c < HID; c++) b = fmaf(s_sh[c], W1src[c * HID + t], b);
            b1eff[t] = b;
        }
    }
}

// ---------------- Pooling + FC ----------------

__global__ void pool_kernel(const float* __restrict__ h, const int* __restrict__ batch,
                            const float* __restrict__ scsh, float* __restrict__ pooled) {
    int gt = blockIdx.x * blockDim.x + threadIdx.x;
    if (gt >= N_NODES * HID) return;
    int node = gt >> 5;
    int c = gt & 31;
    int g = batch[node];
    float v = fmaf(h[gt], scsh[c], scsh[HID + c]);
    atomicAdd(&pooled[g * HID + c], v);
}

__global__ void fc_kernel(const float* __restrict__ pooled, const float* __restrict__ fcw,
                          const float* __restrict__ fcb, float* __restrict__ out) {
    __shared__ float w[HID * OUTD];
    for (int i = threadIdx.x; i < HID * OUTD; i += 256) w[i] = fcw[i];
    __syncthreads();
    int idx = blockIdx.x * 256 + threadIdx.x;
    if (idx >= N_GRAPHS * OUTD) return;
    int g = idx >> 7;
    int o = idx & 127;
    float acc = fcb[o];
#pragma unroll
    for (int k = 0; k < HID; k++) acc = fmaf(pooled[g * HID + k], w[k * OUTD + o], acc);
    out[idx] = fmaxf(acc, 0.f);
}

// ---------------- Launch ----------------

extern "C" void kernel_launch(void* const* d_in, const int* in_sizes, int n_in,
                              void* d_out, int out_size, void* d_ws, size_t ws_size,
                              hipStream_t stream) {
    const float* x = (const float*)d_in[0];
    const int* ei = (const int*)d_in[1];
    const int* batch = (const int*)d_in[2];
    const float* w1_0 = (const float*)d_in[3];
    const float* b1_0 = (const float*)d_in[4];
    const float* w2_0 = (const float*)d_in[5];
    const float* b2_0 = (const float*)d_in[6];
    const float* w1 = (const float*)d_in[7];
    const float* b1 = (const float*)d_in[8];
    const float* w2 = (const float*)d_in[9];
    const float* b2 = (const float*)d_in[10];
    const float* gamma = (const float*)d_in[11];
    const float* beta = (const float*)d_in[12];
    const float* fc_w = (const float*)d_in[13];
    const float* fc_b = (const float*)d_in[14];
    float* out = (float*)d_out;

    const int* e_src = ei;
    const int* e_dst = ei + N_EDGES;

    char* ws = (char*)d_ws;
    size_t off = 0;
    auto alloc = [&](size_t n) {
        void* p = ws + off;
        off += (n + 255) & ~(size_t)255;
        return p;
    };
    int* row_start = (int*)alloc((size_t)(N_NODES + 1) * 4);
    int* csr = (int*)alloc((size_t)N_EDGES * 4);
    int* gcur = (int*)alloc((size_t)NBUCK * 4);
    int* bbase = (int*)alloc((size_t)NBUCK * 4);
    int* staging = (int*)alloc((size_t)NBUCK * BCAP2 * 4);
    float* ybuf = (float*)alloc((size_t)N_NODES * HID * 4);
    float* aggb = (float*)alloc((size_t)N_NODES * HID * 4);
    float* hbuf = (float*)alloc((size_t)N_NODES * HID * 4);
    float* bnsums = (float*)alloc(5 * 2 * HID * 4);
    float* scsh = (float*)alloc(5 * 2 * HID * 4);
    float* w1eff = (float*)alloc(4 * HID * HID * 4);
    float* b1eff = (float*)alloc(4 * HID * 4);
    float* pooled = (float*)alloc((size_t)N_GRAPHS * HID * 4);

    hipMemsetAsync(gcur, 0, (size_t)NBUCK * 4, stream);
    hipMemsetAsync(bnsums, 0, 5 * 2 * HID * 4, stream);
    hipMemsetAsync(pooled, 0, (size_t)N_GRAPHS * HID * 4, stream);

    // CSR build: LDS-staged partition then per-bucket counting sort
    part1_kernel<<<P1_BLOCKS, 256, 0, stream>>>(e_src, e_dst, gcur, staging);
    csrbase_kernel<<<1, 256, 0, stream>>>(gcur, bbase, row_start);
    part2_kernel<<<NBUCK, 256, 0, stream>>>(gcur, bbase, staging, row_start, csr);

    const int nodeBlocks = (N_NODES + 255) / 256;
    const int aggBlocks = (N_NODES * 32 + 255) / 256;  // 12500

    // Layer 0
    proj78_kernel<<<nodeBlocks, 256, 0, stream>>>(x, w1_0, ybuf);
    agg_kernel<<<aggBlocks, 256, 0, stream>>>(ybuf, row_start, csr, aggb);
    mlp2cpl_kernel<<<CPL_BLOCKS, 256, 0, stream>>>(aggb, b1_0, w2_0, b2_0, hbuf, bnsums);
    bnfinW_kernel<<<1, 256, 0, stream>>>(bnsums, gamma, beta, scsh, w1, w1eff, b1eff);

    // Layers 1..4
    for (int l = 1; l < 5; l++) {
        int i = l - 1;
        proj32_kernel<<<CPL_BLOCKS, 256, 0, stream>>>(hbuf, w1eff + (size_t)i * HID * HID,
                                                      b1eff + (size_t)i * HID, ybuf);
        agg_kernel<<<aggBlocks, 256, 0, stream>>>(ybuf, row_start, csr, aggb);
        mlp2cpl_kernel<<<CPL_BLOCKS, 256, 0, stream>>>(
            aggb, b1 + (size_t)i * HID, w2 + (size_t)i * HID * HID, b2 + (size_t)i * HID,
            hbuf, bnsums + l * 2 * HID);
        const float* w1next = (l < 4) ? (w1 + (size_t)l * HID * HID) : nullptr;
        bnfinW_kernel<<<1, 256, 0, stream>>>(bnsums + l * 2 * HID, gamma + l * HID,
                                             beta + l * HID, scsh + l * 2 * HID, w1next,
                                             w1eff + (size_t)l * HID * HID,
                                             b1eff + (size_t)l * HID);
    }

    // Pool + FC
    pool_kernel<<<(N_NODES * HID + 255) / 256, 256, 0, stream>>>(hbuf, batch, scsh + 4 * 2 * HID,
                                                                 pooled);
    fc_kernel<<<(N_GRAPHS * OUTD + 255) / 256, 256, 0, stream>>>(pooled, fc_w, fc_b, out);
}

// Round 9
// 522.177 us; speedup vs baseline: 1.5925x; 1.5925x over previous
//
#include <hip/hip_runtime.h>

#define N_NODES 100000
#define N_EDGES 3200000
#define N_GRAPHS 2048
#define MOL 78
#define HID 32
#define OUTD 128
#define BN_EPS 1e-5f

// Partition: buckets of 256 nodes (dst >> 8)
#define NBUCK ((N_NODES + 255) / 256)  // 391
#define BCAP2 9216                     // mean 8184, sigma ~90 -> +11 sigma
#define EPB 4096                       // edges per part1 block
#define P1_BLOCKS ((N_EDGES + EPB - 1) / EPB)  // 782

#define NPH 4                             // nodes per half-wave (matvec kernels)
#define CPL_BLOCKS (N_NODES / (8 * NPH))  // 3125 (exact)

#define NCOPY 64  // BN-sum accumulator copies (kills same-address atomic serialization)

// ---------------- CSR build: LDS-staged two-pass bucket sort ----------------

__global__ __launch_bounds__(256) void part1_kernel(const int* __restrict__ src,
                                                    const int* __restrict__ dst,
                                                    int* __restrict__ gcur,
                                                    int* __restrict__ staging) {
    __shared__ int hist[NBUCK];
    __shared__ int lofs[NBUCK];
    __shared__ int lcur[NBUCK];
    __shared__ int gb[NBUCK];
    __shared__ int pk[EPB];
    __shared__ unsigned short bkt[EPB];
    __shared__ int sc[256];
    const int t = threadIdx.x;
    const int base = blockIdx.x * EPB;
    const int nedge = min(EPB, N_EDGES - base);

    for (int i = t; i < NBUCK; i += 256) hist[i] = 0;
    __syncthreads();
    for (int i = t; i < nedge; i += 256) atomicAdd(&hist[dst[base + i] >> 8], 1);
    __syncthreads();

    int a0 = (2 * t < NBUCK) ? hist[2 * t] : 0;
    int a1 = (2 * t + 1 < NBUCK) ? hist[2 * t + 1] : 0;
    int tot = a0 + a1;
    sc[t] = tot;
    __syncthreads();
    for (int off = 1; off < 256; off <<= 1) {
        int add = (t >= off) ? sc[t - off] : 0;
        __syncthreads();
        sc[t] += add;
        __syncthreads();
    }
    int excl = sc[t] - tot;
    if (2 * t < NBUCK) { lofs[2 * t] = excl; lcur[2 * t] = excl; }
    if (2 * t + 1 < NBUCK) { lofs[2 * t + 1] = excl + a0; lcur[2 * t + 1] = excl + a0; }
    __syncthreads();

    for (int i = t; i < nedge; i += 256) {
        int d = dst[base + i];
        int s = src[base + i];
        int b = d >> 8;
        int p = atomicAdd(&lcur[b], 1);
        pk[p] = (s << 8) | (d & 255);
        bkt[p] = (unsigned short)b;
    }
    __syncthreads();

    for (int b = t; b < NBUCK; b += 256) {
        int c = lcur[b] - lofs[b];
        gb[b] = c ? atomicAdd(&gcur[b], c) : 0;
    }
    __syncthreads();

    for (int i = t; i < nedge; i += 256) {
        int b = bkt[i];
        staging[(size_t)b * BCAP2 + gb[b] + (i - lofs[b])] = pk[i];
    }
}

__global__ void csrbase_kernel(const int* __restrict__ gcur, int* __restrict__ bbase,
                               int* __restrict__ row_start) {
    int t = threadIdx.x;
    int a0 = (2 * t < NBUCK) ? gcur[2 * t] : 0;
    int a1 = (2 * t + 1 < NBUCK) ? gcur[2 * t + 1] : 0;
    int tot = a0 + a1;
    __shared__ int sc[256];
    sc[t] = tot;
    __syncthreads();
    for (int off = 1; off < 256; off <<= 1) {
        int add = (t >= off) ? sc[t - off] : 0;
        __syncthreads();
        sc[t] += add;
        __syncthreads();
    }
    int excl = sc[t] - tot;
    if (2 * t < NBUCK) bbase[2 * t] = excl;
    if (2 * t + 1 < NBUCK) bbase[2 * t + 1] = excl + a0;
    if (t == 0) row_start[N_NODES] = N_EDGES;
}

__global__ __launch_bounds__(256) void part2_kernel(const int* __restrict__ gcur,
                                                    const int* __restrict__ bbase,
                                                    const int* __restrict__ staging,
                                                    int* __restrict__ row_start,
                                                    int* __restrict__ csr) {
    int b = blockIdx.x, t = threadIdx.x;
    __shared__ int ldeg[256];
    __shared__ int lex[256];
    __shared__ int sc[256];
    ldeg[t] = 0;
    __syncthreads();
    int cnt = gcur[b];
    int base = bbase[b];
    const int* sp = staging + (size_t)b * BCAP2;
    for (int i = t; i < cnt; i += 256) atomicAdd(&ldeg[sp[i] & 255], 1);
    __syncthreads();
    int v = ldeg[t];
    sc[t] = v;
    __syncthreads();
    for (int off = 1; off < 256; off <<= 1) {
        int add = (t >= off) ? sc[t - off] : 0;
        __syncthreads();
        sc[t] += add;
        __syncthreads();
    }
    int excl = sc[t] - v;
    int node = b * 256 + t;
    if (node < N_NODES) row_start[node] = base + excl;
    lex[t] = base + excl;
    __syncthreads();
    for (int i = t; i < cnt; i += 256) {
        int pk = sp[i];
        int p = atomicAdd(&lex[pk & 255], 1);
        csr[p] = pk >> 8;
    }
}

// ---------------- Layer-0 projection (78 -> 32), thread-per-node ----------------

__global__ __launch_bounds__(256) void proj78_kernel(const float* __restrict__ in,
                                                     const float* __restrict__ W1,
                                                     float* __restrict__ y) {
    __shared__ float w1s[MOL * HID];
    for (int i = threadIdx.x; i < MOL * HID; i += 256) w1s[i] = W1[i];
    __syncthreads();
    const int node = blockIdx.x * 256 + threadIdx.x;
    if (node >= N_NODES) return;
    const float* row = in + (size_t)node * MOL;
    float acc[HID];
#pragma unroll
    for (int j = 0; j < HID; j++) acc[j] = 0.f;
    const float4* w1v = (const float4*)w1s;
    for (int k = 0; k < MOL; k++) {
        float xv = row[k];
#pragma unroll
        for (int q = 0; q < 8; q++) {
            float4 wv = w1v[k * 8 + q];
            acc[4 * q + 0] = fmaf(xv, wv.x, acc[4 * q + 0]);
            acc[4 * q + 1] = fmaf(xv, wv.y, acc[4 * q + 1]);
            acc[4 * q + 2] = fmaf(xv, wv.z, acc[4 * q + 2]);
            acc[4 * q + 3] = fmaf(xv, wv.w, acc[4 * q + 3]);
        }
    }
    float4* o = (float4*)(y + (size_t)node * HID);
#pragma unroll
    for (int q = 0; q < 8; q++)
        o[q] = make_float4(acc[4 * q], acc[4 * q + 1], acc[4 * q + 2], acc[4 * q + 3]);
}

// ---------------- Aggregation: pure 32-dim f32 sum over CSR ----------------
// One half-wave per node, 12500 blocks: 4 slots x 8 lanes x float4, unroll x2.

__global__ __launch_bounds__(256) void agg_kernel(const float* __restrict__ y,
                                                  const int* __restrict__ rs,
                                                  const int* __restrict__ csr,
                                                  float* __restrict__ agg) {
    int gt = blockIdx.x * blockDim.x + threadIdx.x;
    int node = gt >> 5;
    if (node >= N_NODES) return;
    int hl = threadIdx.x & 31;  // lane within half-wave
    int s = hl >> 3;            // edge slot 0..3
    int q = hl & 7;             // float4 quad (channels 4q..4q+3)
    const float4* rows = (const float4*)y;
    float4 acc = (s == 0) ? rows[(size_t)node * 8 + q] : make_float4(0.f, 0.f, 0.f, 0.f);
    int e0 = rs[node], e1 = rs[node + 1];
    int k = e0 + s;
    for (; k + 4 < e1; k += 8) {
        int j0 = csr[k];
        int j1 = csr[k + 4];
        float4 v0 = rows[(size_t)j0 * 8 + q];
        float4 v1 = rows[(size_t)j1 * 8 + q];
        acc.x += v0.x + v1.x;
        acc.y += v0.y + v1.y;
        acc.z += v0.z + v1.z;
        acc.w += v0.w + v1.w;
    }
    if (k < e1) {
        int j = csr[k];
        float4 v = rows[(size_t)j * 8 + q];
        acc.x += v.x;
        acc.y += v.y;
        acc.z += v.z;
        acc.w += v.w;
    }
#pragma unroll
    for (int m = 8; m <= 16; m <<= 1) {
        acc.x += __shfl_xor(acc.x, m, 32);
        acc.y += __shfl_xor(acc.y, m, 32);
        acc.z += __shfl_xor(acc.z, m, 32);
        acc.w += __shfl_xor(acc.w, m, 32);
    }
    if (s == 0) ((float4*)agg)[(size_t)node * 8 + q] = acc;
}

// ---------------- MLP second half, channel-per-lane ----------------
// BN sums: per-lane local -> LDS -> 64-copy global accumulator (kills the
// same-address atomic serialization that cost ~83 us/layer).

__global__ __launch_bounds__(256) void mlp2cpl_kernel(const float* __restrict__ agg,
                                                      const float* __restrict__ B1,
                                                      const float* __restrict__ W2,
                                                      const float* __restrict__ B2,
                                                      float* __restrict__ out,
                                                      float* __restrict__ sums) {
    __shared__ float ldsv[8][NPH][HID];
    __shared__ float ssum[64];
    const int t = threadIdx.x;
    const int hw = t >> 5;
    const int c = t & 31;
    if (t < 64) ssum[t] = 0.f;
    float w2col[32];
#pragma unroll
    for (int k = 0; k < 32; k++) w2col[k] = W2[k * 32 + c];
    const float b1c = B1[c], b2c = B2[c];
    const int n0 = (blockIdx.x * 8 + hw) * NPH;
#pragma unroll
    for (int u = 0; u < NPH; u++) {
        float v = fmaxf(agg[(size_t)(n0 + u) * 32 + c] + b1c, 0.f);
        ldsv[hw][u][c] = v;
    }
    __syncthreads();
    float sl = 0.f, sq = 0.f;
#pragma unroll
    for (int u = 0; u < NPH; u++) {
        float h = b2c;
        const float4* vv4 = (const float4*)&ldsv[hw][u][0];
#pragma unroll
        for (int q = 0; q < 8; q++) {
            float4 vv = vv4[q];
            h = fmaf(vv.x, w2col[4 * q + 0], h);
            h = fmaf(vv.y, w2col[4 * q + 1], h);
            h = fmaf(vv.z, w2col[4 * q + 2], h);
            h = fmaf(vv.w, w2col[4 * q + 3], h);
        }
        h = fmaxf(h, 0.f);
        out[(size_t)(n0 + u) * 32 + c] = h;
        sl += h;
        sq += h * h;
    }
    atomicAdd(&ssum[c], sl);
    atomicAdd(&ssum[32 + c], sq);
    __syncthreads();
    if (t < 64) atomicAdd(&sums[(blockIdx.x & (NCOPY - 1)) * 64 + t], ssum[t]);
}

// ---------------- Projection 32->32 with pre-folded affine (channel-per-lane) ------

__global__ __launch_bounds__(256) void proj32_kernel(const float* __restrict__ h,
                                                     const float* __restrict__ W1e,
                                                     const float* __restrict__ b1e,
                                                     float* __restrict__ y) {
    __shared__ float ldsh[8][NPH][32];
    const int t = threadIdx.x;
    const int hw = t >> 5;
    const int c = t & 31;
    float w1col[32];
#pragma unroll
    for (int k = 0; k < 32; k++) w1col[k] = W1e[k * 32 + c];
    const float bc = b1e[c];
    const int n0 = (blockIdx.x * 8 + hw) * NPH;
#pragma unroll
    for (int u = 0; u < NPH; u++) {
        int n = n0 + u;
        ldsh[hw][u][c] = h[(size_t)n * 32 + c];
    }
    __syncthreads();
#pragma unroll
    for (int u = 0; u < NPH; u++) {
        int n = n0 + u;
        float acc = bc;
        const float4* hh4 = (const float4*)&ldsh[hw][u][0];
#pragma unroll
        for (int q = 0; q < 8; q++) {
            float4 hh = hh4[q];
            acc = fmaf(hh.x, w1col[4 * q + 0], acc);
            acc = fmaf(hh.y, w1col[4 * q + 1], acc);
            acc = fmaf(hh.z, w1col[4 * q + 2], acc);
            acc = fmaf(hh.w, w1col[4 * q + 3], acc);
        }
        y[(size_t)n * 32 + c] = acc;
    }
}

// ---------------- BN finalize: fold NCOPY copies, then (optional) W1 fold ----------

__global__ void bnfinW_kernel(const float* __restrict__ sums, const float* __restrict__ g,
                              const float* __restrict__ bt, float* __restrict__ scsh,
                              const float* __restrict__ W1src, float* __restrict__ w1eff,
                              float* __restrict__ b1eff) {
    __shared__ float red[64];
    __shared__ float s_sc[HID], s_sh[HID];
    int t = threadIdx.x;
    if (t < 64) {
        float acc = 0.f;
#pragma unroll 8
        for (int k = 0; k < NCOPY; k++) acc += sums[k * 64 + t];
        red[t] = acc;
    }
    __syncthreads();
    if (t < HID) {
        float m = red[t] * (1.0f / N_NODES);
        float var = red[HID + t] * (1.0f / N_NODES) - m * m;
        var = fmaxf(var, 0.f);
        float sc = g[t] * rsqrtf(var + BN_EPS);
        float sh = bt[t] - m * sc;
        scsh[t] = sc;
        scsh[HID + t] = sh;
        s_sc[t] = sc;
        s_sh[t] = sh;
    }
    __syncthreads();
    if (W1src) {
        for (int idx = t; idx < HID * HID; idx += 256)
            w1eff[idx] = s_sc[idx >> 5] * W1src[idx];
        if (t < HID) {
            float b = 0.f;
            for (int c = 0; c < HID; c++) b = fmaf(s_sh[c], W1src[c * HID + t], b);
            b1eff[t] = b;
        }
    }
}

// ---------------- Pooling + FC ----------------

__global__ void pool_kernel(const float* __restrict__ h, const int* __restrict__ batch,
                            const float* __restrict__ scsh, float* __restrict__ pooled) {
    int gt = blockIdx.x * blockDim.x + threadIdx.x;
    if (gt >= N_NODES * HID) return;
    int node = gt >> 5;
    int c = gt & 31;
    int g = batch[node];
    float v = fmaf(h[gt], scsh[c], scsh[HID + c]);
    atomicAdd(&pooled[g * HID + c], v);
}

__global__ void fc_kernel(const float* __restrict__ pooled, const float* __restrict__ fcw,
                          const float* __restrict__ fcb, float* __restrict__ out) {
    __shared__ float w[HID * OUTD];
    for (int i = threadIdx.x; i < HID * OUTD; i += 256) w[i] = fcw[i];
    __syncthreads();
    int idx = blockIdx.x * 256 + threadIdx.x;
    if (idx >= N_GRAPHS * OUTD) return;
    int g = idx >> 7;
    int o = idx & 127;
    float acc = fcb[o];
#pragma unroll
    for (int k = 0; k < HID; k++) acc = fmaf(pooled[g * HID + k], w[k * OUTD + o], acc);
    out[idx] = fmaxf(acc, 0.f);
}

// ---------------- Launch ----------------

extern "C" void kernel_launch(void* const* d_in, const int* in_sizes, int n_in,
                              void* d_out, int out_size, void* d_ws, size_t ws_size,
                              hipStream_t stream) {
    const float* x = (const float*)d_in[0];
    const int* ei = (const int*)d_in[1];
    const int* batch = (const int*)d_in[2];
    const float* w1_0 = (const float*)d_in[3];
    const float* b1_0 = (const float*)d_in[4];
    const float* w2_0 = (const float*)d_in[5];
    const float* b2_0 = (const float*)d_in[6];
    const float* w1 = (const float*)d_in[7];
    const float* b1 = (const float*)d_in[8];
    const float* w2 = (const float*)d_in[9];
    const float* b2 = (const float*)d_in[10];
    const float* gamma = (const float*)d_in[11];
    const float* beta = (const float*)d_in[12];
    const float* fc_w = (const float*)d_in[13];
    const float* fc_b = (const float*)d_in[14];
    float* out = (float*)d_out;

    const int* e_src = ei;
    const int* e_dst = ei + N_EDGES;

    char* ws = (char*)d_ws;
    size_t off = 0;
    auto alloc = [&](size_t n) {
        void* p = ws + off;
        off += (n + 255) & ~(size_t)255;
        return p;
    };
    int* row_start = (int*)alloc((size_t)(N_NODES + 1) * 4);
    int* csr = (int*)alloc((size_t)N_EDGES * 4);
    int* gcur = (int*)alloc((size_t)NBUCK * 4);
    int* bbase = (int*)alloc((size_t)NBUCK * 4);
    int* staging = (int*)alloc((size_t)NBUCK * BCAP2 * 4);
    float* ybuf = (float*)alloc((size_t)N_NODES * HID * 4);
    float* aggb = (float*)alloc((size_t)N_NODES * HID * 4);
    float* hbuf = (float*)alloc((size_t)N_NODES * HID * 4);
    float* bnsums = (float*)alloc((size_t)5 * NCOPY * 64 * 4);
    float* scsh = (float*)alloc(5 * 2 * HID * 4);
    float* w1eff = (float*)alloc(4 * HID * HID * 4);
    float* b1eff = (float*)alloc(4 * HID * 4);
    float* pooled = (float*)alloc((size_t)N_GRAPHS * HID * 4);

    hipMemsetAsync(gcur, 0, (size_t)NBUCK * 4, stream);
    hipMemsetAsync(bnsums, 0, (size_t)5 * NCOPY * 64 * 4, stream);
    hipMemsetAsync(pooled, 0, (size_t)N_GRAPHS * HID * 4, stream);

    // CSR build: LDS-staged partition then per-bucket counting sort
    part1_kernel<<<P1_BLOCKS, 256, 0, stream>>>(e_src, e_dst, gcur, staging);
    csrbase_kernel<<<1, 256, 0, stream>>>(gcur, bbase, row_start);
    part2_kernel<<<NBUCK, 256, 0, stream>>>(gcur, bbase, staging, row_start, csr);

    const int nodeBlocks = (N_NODES + 255) / 256;
    const int aggBlocks = (N_NODES * 32 + 255) / 256;  // 12500

    // Layer 0
    proj78_kernel<<<nodeBlocks, 256, 0, stream>>>(x, w1_0, ybuf);
    agg_kernel<<<aggBlocks, 256, 0, stream>>>(ybuf, row_start, csr, aggb);
    mlp2cpl_kernel<<<CPL_BLOCKS, 256, 0, stream>>>(aggb, b1_0, w2_0, b2_0, hbuf, bnsums);
    bnfinW_kernel<<<1, 256, 0, stream>>>(bnsums, gamma, beta, scsh, w1, w1eff, b1eff);

    // Layers 1..4
    for (int l = 1; l < 5; l++) {
        int i = l - 1;
        proj32_kernel<<<CPL_BLOCKS, 256, 0, stream>>>(hbuf, w1eff + (size_t)i * HID * HID,
                                                      b1eff + (size_t)i * HID, ybuf);
        agg_kernel<<<aggBlocks, 256, 0, stream>>>(ybuf, row_start, csr, aggb);
        mlp2cpl_kernel<<<CPL_BLOCKS, 256, 0, stream>>>(
            aggb, b1 + (size_t)i * HID, w2 + (size_t)i * HID * HID, b2 + (size_t)i * HID,
            hbuf, bnsums + (size_t)l * NCOPY * 64);
        const float* w1next = (l < 4) ? (w1 + (size_t)l * HID * HID) : nullptr;
        bnfinW_kernel<<<1, 256, 0, stream>>>(bnsums + (size_t)l * NCOPY * 64, gamma + l * HID,
                                             beta + l * HID, scsh + l * 2 * HID, w1next,
                                             w1eff + (size_t)l * HID * HID,
                                             b1eff + (size_t)l * HID);
    }

    // Pool + FC
    pool_kernel<<<(N_NODES * HID + 255) / 256, 256, 0, stream>>>(hbuf, batch, scsh + 4 * 2 * HID,
                                                                 pooled);
    fc_kernel<<<(N_GRAPHS * OUTD + 255) / 256, 256, 0, stream>>>(pooled, fc_w, fc_b, out);
}